// Round 16
// baseline (538.279 us; speedup 1.0000x reference)
//
#include <hip/hip_runtime.h>
#include <cstdint>
#include <cstddef>

typedef __bf16 bf16;
typedef __bf16 bf16x8 __attribute__((ext_vector_type(8)));
typedef __bf16 bf16x4 __attribute__((ext_vector_type(4)));
typedef float  f32x4  __attribute__((ext_vector_type(4)));

#define NB 7
static constexpr int Bq = 2, Sq = 4096, Dm = 1024, Dff = 4096;
static constexpr int Mrows = Bq * Sq;     // 8192
static constexpr int NCH = Sq / 4;        // 1024 chunks per (b,h)
static constexpr int CSW = 464;           // padded prefix-state row width

template <int V> struct ic { static constexpr int value = V; };

__device__ __forceinline__ void gload16(const void* g, void* l) {
  __builtin_amdgcn_global_load_lds((__attribute__((address_space(1))) void*)g,
                                   (__attribute__((address_space(3))) void*)l,
                                   16, 0, 0);
}

template <int N> __device__ __forceinline__ void wait_vmcnt() {
  asm volatile("s_waitcnt vmcnt(%0)" :: "n"(N) : "memory");
}
__device__ __forceinline__ void wait_lgkm0() {
  asm volatile("s_waitcnt lgkmcnt(0)" ::: "memory");
}
__device__ __forceinline__ void SB() { __builtin_amdgcn_sched_barrier(0); }

__device__ __forceinline__ float gelu_f(float x) {
  const float c = 0.79788456080286535588f;
  float z = c * (x + 0.044715f * x * x * x);
  float t = 1.f - 2.f / (__expf(2.f * z) + 1.f);   // tanh(z)
  return 0.5f * x * (1.f + t);
}

// ---------------- batched f32 -> bf16 convert (10 regions, 1 launch) ----------
struct CvtA {
  const float* s[10];
  bf16* d[10];
  int start[11];
};
__global__ __launch_bounds__(256) void cvt10(CvtA a) {
  const int i = blockIdx.x * 256 + threadIdx.x;
  int r = 0;
#pragma unroll
  for (int k = 1; k < 10; ++k) r += (i >= a.start[k]);
  const int o = i - a.start[r];
  f32x4 v = *(const f32x4*)&a.s[r][(size_t)o * 4];
  bf16x4 ov;
#pragma unroll
  for (int e = 0; e < 4; ++e) ov[e] = (bf16)v[e];
  *(bf16x4*)&a.d[r][(size_t)o * 4] = ov;
}

// ---------------- LayerNorm (ddof=1, /(std+eps)) -> bf16 ----------------
__global__ __launch_bounds__(256) void ln_kernel(const float* __restrict__ x,
                                                 const float* __restrict__ alpha,
                                                 const float* __restrict__ beta,
                                                 bf16* __restrict__ out) {
  const int row = blockIdx.x, tid = threadIdx.x;
  const float* xr = x + (size_t)row * Dm;
  f32x4 v = *(const f32x4*)&xr[tid * 4];
  float s  = v[0] + v[1] + v[2] + v[3];
  float s2 = v[0]*v[0] + v[1]*v[1] + v[2]*v[2] + v[3]*v[3];
#pragma unroll
  for (int o = 32; o > 0; o >>= 1) { s += __shfl_xor(s, o); s2 += __shfl_xor(s2, o); }
  __shared__ float red[8];
  const int wid = tid >> 6, lane = tid & 63;
  if (lane == 0) { red[wid] = s; red[wid + 4] = s2; }
  __syncthreads();
  s  = red[0] + red[1] + red[2] + red[3];
  s2 = red[4] + red[5] + red[6] + red[7];
  const float mean = s * (1.f / 1024.f);
  float var = (s2 - s * mean) * (1.f / 1023.f);
  var = fmaxf(var, 0.f);
  const float inv = 1.f / (sqrtf(var) + 1e-6f);
  f32x4 a4 = *(const f32x4*)&alpha[tid * 4];
  f32x4 b4 = *(const f32x4*)&beta[tid * 4];
  bf16x4 o4;
#pragma unroll
  for (int e = 0; e < 4; ++e) o4[e] = (bf16)(a4[e] * (v[e] - mean) * inv + b4[e]);
  *(bf16x4*)&out[(size_t)row * Dm + tid * 4] = o4;
}

// ====== 128x256 GEMM, BK=32, 4 waves of 64x128 (fat wave tile), 48KB LDS ======
// LDS-read model: 12 KB reads per 32 MFMA/wave (42.7 FLOP/B) -> cap 40% vs the
// 30% cap of 64x64 wave tiles (which matched measured 29%). 2 blocks/CU
// (48KB LDS, ~200 VGPR) preserves cross-block overlap. Sync = proven r10
// skeleton: homogeneous gload_lds queue, counted vmcnt(6), lgkm0+barrier
// before buffer overwrite. Swizzle for 32-col tiles: unit ^= (row>>1)&3
// (2-way max conflict), pre-applied on global source.
// MODE 0: bf16 | 1:+res->bf16 | 2:+res->f32 | 3:+bias,gelu->bf16 | 4:+bias+res->f32
template <int MODE>
__global__ __launch_bounds__(256, 2) void gemmW(
    const bf16* __restrict__ A, const bf16* __restrict__ Bw,
    int M, int N, int K,
    const float* __restrict__ bias, const float* __restrict__ res,
    float* __restrict__ outF, bf16* __restrict__ outB) {
  __shared__ __align__(16) char lds[49152];   // A:2x8KB @0,8192; B:2x16KB @16384,32768

  const int tid = threadIdx.x;
  const int lane = tid & 63, wid = tid >> 6;
  const int wm = wid >> 1, wn = wid & 1;      // 2m x 2n waves, wave tile 64x128

  // ---- supertile 16x4 (64 blocks = one XCD residency), XCD-contiguous ----
  const int nwg = gridDim.x;
  const int nc = N >> 8;                      // block-cols (256 wide): 4/8/12/16
  const int nsc = nc >> 2;
  const int lin = (blockIdx.x & 7) * (nwg >> 3) + (blockIdx.x >> 3);
  const int s = lin >> 6, w = lin & 63;
  const int sr = s / nsc, sc = s - sr * nsc;
  const int bm = (sr * 16 + (w >> 2)) * 128;
  const int bn = (sc * 4 + (w & 3)) * 256;
  const int NT = K >> 5;                      // K-tiles of 32

  // ---- staging: 6 gload16/thread/tile (A 2 sweeps, B 4 sweeps of 64 rows) ----
  const int srow4 = tid >> 2;                 // 0..63 (row within sweep)
  const int cu = ((tid & 3) ^ ((srow4 >> 1) & 3)) * 8;   // inv-swizzled col (bf16)
  const bf16* pSA = A  + (size_t)(bm + srow4) * K + cu;
  const bf16* pSB = Bw + (size_t)(bn + srow4) * K + cu;
  const size_t swK = (size_t)64 * K;          // sweep stride
  const int dA = wid * 1024 + (lane & 63) * 16;

  auto stage = [&](int buf, int t) {
#pragma unroll
    for (int s2 = 0; s2 < 2; ++s2)
      gload16(pSA + s2 * swK + (size_t)t * 32, &lds[buf * 8192 + s2 * 4096 + dA]);
#pragma unroll
    for (int s2 = 0; s2 < 4; ++s2)
      gload16(pSB + s2 * swK + (size_t)t * 32, &lds[16384 + buf * 16384 + s2 * 4096 + dA]);
  };

  // ---- LDS read offsets (swizzled, loop-invariant) ----
  const int lr = lane & 15, uo = lane >> 4;   // uo 0..3 = k-quarter
  const int swz = (lr >> 1) & 3;
  const int rdA = (wm * 64 + lr) * 64 + ((uo ^ swz) * 16);          // + i*1024
  const int rdB = 16384 + (wn * 128 + lr) * 64 + ((uo ^ swz) * 16); // + j*1024

  f32x4 acc[4][8] = {};
  bf16x8 a[4], b[8];

  // prologue: tiles 0 and 1 staged
  stage(0, 0);
  stage(1, 1);
  wait_vmcnt<6>();                 // tile 0 fully in LDS
  __builtin_amdgcn_s_barrier();

  auto TILE = [&](auto BUFC, int tt) {
    constexpr int BUF = decltype(BUFC)::value;
#pragma unroll
    for (int i = 0; i < 4; ++i)
      a[i] = *(const bf16x8*)&lds[rdA + BUF * 8192 + i * 1024];
#pragma unroll
    for (int j = 0; j < 8; ++j)
      b[j] = *(const bf16x8*)&lds[rdB + BUF * 16384 + j * 1024];
    wait_lgkm0(); SB();
    __builtin_amdgcn_s_barrier(); SB();       // all waves' reads done -> buf free

    if (tt + 2 < NT) stage(BUF, tt + 2);
    // unpinned: compiler interleaves staging with MFMA
#pragma unroll
    for (int i = 0; i < 4; ++i)
#pragma unroll
      for (int j = 0; j < 8; ++j)
        acc[i][j] = __builtin_amdgcn_mfma_f32_16x16x32_bf16(a[i], b[j], acc[i][j], 0, 0, 0);
    SB();
    if (tt < NT - 2) wait_vmcnt<6>();
    else             wait_vmcnt<0>();
    __builtin_amdgcn_s_barrier(); SB();
  };

  for (int t = 0; t < NT; t += 2) {
    TILE(ic<0>{}, t);
    TILE(ic<1>{}, t + 1);
  }

  // ---- epilogue ----
#pragma unroll
  for (int f = 0; f < 4; ++f) {
    const int r0 = bm + wm * 64 + f * 16 + (lane >> 4) * 4;
#pragma unroll
    for (int g = 0; g < 8; ++g) {
      const int c = bn + wn * 128 + g * 16 + (lane & 15);
      float bv = 0.f;
      if (MODE == 3 || MODE == 4) bv = bias[c];
#pragma unroll
      for (int r = 0; r < 4; ++r) {
        const size_t idx = (size_t)(r0 + r) * N + c;
        float v = acc[f][g][r];
        if (MODE == 1 || MODE == 2) v += res[idx];
        if (MODE == 3) v = gelu_f(v + bv);
        if (MODE == 4) v += bv + res[idx];
        if (MODE == 0 || MODE == 1 || MODE == 3) outB[idx] = (bf16)v;
        else outF[idx] = v;
      }
    }
  }
}

// ------- fused Performer chunk-sums + segment scan (block = 1 segment) -------
// CS stored in bf16 (halves traffic); segtot (raw segment totals) stays f32.
__global__ __launch_bounds__(512) void perf_cs(
    const bf16* __restrict__ kmat, const bf16* __restrict__ vmat, int ld,
    const float* __restrict__ omega, bf16* __restrict__ CS,
    float* __restrict__ segtot) {
  const int tid = threadIdx.x;
  const int bh = blockIdx.y, b = bh >> 4, h = bh & 15;
  const int seg = blockIdx.x;
  const int s0 = seg * 512;
  __shared__ __align__(16) bf16 vs[512][64];   // XOR-swizzled, 64 KB
  __shared__ float kps[512][8];                // 16 KB
  __shared__ float oms[448];

  {
    const bf16* vb = vmat + ((size_t)(b * Sq + s0)) * ld + h * 64;
#pragma unroll
    for (int p = 0; p < 8; ++p) {
      const int row = p * 64 + (tid >> 3), c16 = (tid & 7) * 8;
      *(uint4*)&vs[row][c16 ^ ((row & 7) * 8)] =
          *(const uint4*)&vb[(size_t)row * ld + c16];
    }
  }
  if (tid < 448) oms[tid] = omega[tid];
  __syncthreads();

  {
    const int row = tid;
    const bf16* kr = kmat + ((size_t)(b * Sq + s0 + row)) * ld + h * 64;
    bf16x8 kv[8];
#pragma unroll
    for (int q = 0; q < 8; ++q) kv[q] = *(const bf16x8*)&kr[q * 8];
    float f[NB];
#pragma unroll
    for (int n = 0; n < NB; ++n) f[n] = 0.f;
#pragma unroll
    for (int d = 0; d < 64; ++d) {
      const float kd = (float)kv[d >> 3][d & 7];
#pragma unroll
      for (int n = 0; n < NB; ++n) f[n] += kd * oms[n * 64 + d];
    }
    float sum = 1e-6f, e[NB];
#pragma unroll
    for (int n = 0; n < NB; ++n) { e[n] = __expf(-0.5f * f[n] * f[n]); sum += e[n]; }
    const float inv = 1.f / sum;
#pragma unroll
    for (int n = 0; n < NB; ++n) kps[row][n] = e[n] * inv;
    kps[row][7] = 0.f;
  }
  __syncthreads();

  if (tid < CSW) {
    const int comp = tid;
    bf16* outb = CS + ((size_t)bh * NCH + seg * 128) * CSW;
    float r = 0.f;
    if (comp < 8) {
      for (int c = 0; c < 128; ++c) {
        if (comp < 7)
          r += kps[4*c][comp] + kps[4*c+1][comp] + kps[4*c+2][comp] + kps[4*c+3][comp];
        outb[(size_t)c * CSW + comp] = (bf16)r;
      }
    } else if (comp < 456) {
      const int n = (comp - 8) >> 6, d = (comp - 8) & 63;
      for (int c = 0; c < 128; ++c) {
#pragma unroll
        for (int i = 0; i < 4; ++i) {
          const int row = 4 * c + i;
          r += kps[row][n] * (float)vs[row][d ^ ((row & 7) * 8)];
        }
        outb[(size_t)c * CSW + comp] = (bf16)r;
      }
    } else {
      for (int c = 0; c < 128; ++c) outb[(size_t)c * CSW + comp] = (bf16)0.f;
    }
    segtot[((size_t)bh * 8 + seg) * CSW + comp] = r;
  }
}

// ---------------- Performer output (computes its own segment prefix) ----------------
__global__ __launch_bounds__(256) void perf_out(
    const bf16* __restrict__ qmat, int ldq, const float* __restrict__ omega,
    const bf16* __restrict__ CS, const float* __restrict__ segtot,
    bf16* __restrict__ attn) {
  const int tid = threadIdx.x;
  const int bh = blockIdx.y, b = bh >> 4, h = bh & 15;
  const int s0 = blockIdx.x * 128;
  const int cg0 = s0 >> 2;
  const int seg = cg0 >> 7;
  __shared__ __align__(16) float Ps[32 * CSW];
  __shared__ float qps[128][8];
  __shared__ float oms[NB * 64];
  __shared__ float offs[CSW];

  for (int c = tid; c < CSW; c += 256) {
    float o = 0.f;
    for (int ss = 0; ss < seg; ++ss) o += segtot[((size_t)bh * 8 + ss) * CSW + c];
    offs[c] = o;
  }
  if (tid < 224) { oms[tid] = omega[tid]; oms[tid + 224] = omega[tid + 224]; }
  __syncthreads();

  {
    const bf16* src = CS + ((size_t)bh * NCH + cg0) * CSW;
    for (int i = tid; i < 32 * CSW / 4; i += 256) {
      bf16x4 a4 = *(const bf16x4*)&src[(size_t)i * 4];
      const int c0 = (i % (CSW / 4)) * 4;
      f32x4 o;
#pragma unroll
      for (int e = 0; e < 4; ++e) o[e] = (float)a4[e] + offs[c0 + e];
      *(f32x4*)&Ps[i * 4] = o;
    }
  }
  __syncthreads();
  {
    const int p = tid >> 1, half = tid & 1;
    const bf16* qr = qmat + ((size_t)(b * Sq + s0 + p)) * ldq + h * 64 + half * 32;
    bf16x8 qv[4];
#pragma unroll
    for (int q = 0; q < 4; ++q) qv[q] = *(const bf16x8*)&qr[q * 8];
    float f[NB];
#pragma unroll
    for (int n = 0; n < NB; ++n) f[n] = 0.f;
#pragma unroll
    for (int d = 0; d < 32; ++d) {
      float qd = (float)qv[d >> 3][d & 7];
#pragma unroll
      for (int n = 0; n < NB; ++n) f[n] += qd * oms[n * 64 + half * 32 + d];
    }
    float sum = 1e-6f;
    float e[NB];
#pragma unroll
    for (int n = 0; n < NB; ++n) {
      float full = f[n] + __shfl_xor(f[n], 1);
      e[n] = __expf(-0.5f * full * full);
      sum += e[n];
    }
    float inv = 1.f / sum;
    if (half == 0) {
      float den = 1e-6f;
      const float* Pr = &Ps[(p >> 2) * CSW];
#pragma unroll
      for (int n = 0; n < NB; ++n) {
        float qn = e[n] * inv;
        qps[p][n] = qn;
        den += qn * Pr[n];
      }
      qps[p][7] = 1.f / den;
    }
  }
  __syncthreads();
  {
    const int d = tid & 63, w = tid >> 6;
    for (int qq = w; qq < 128; qq += 4) {
      const float* Pr = &Ps[(qq >> 2) * CSW + 8 + d];
      float num = 0.f;
#pragma unroll
      for (int n = 0; n < NB; ++n) num += qps[qq][n] * Pr[n * 64];
      attn[((size_t)(b * Sq + s0 + qq)) * Dm + h * 64 + d] = (bf16)(num * qps[qq][7]);
    }
  }
}

// ---------------------------------------------------------------------------
extern "C" void kernel_launch(void* const* d_in, const int* in_sizes, int n_in,
                              void* d_out, int out_size, void* d_ws, size_t ws_size,
                              hipStream_t stream) {
  const float* x    = (const float*)d_in[0];
  const float* lto  = (const float*)d_in[1];
  const float* w_s[4] = {(const float*)d_in[2], (const float*)d_in[3],
                         (const float*)d_in[4], (const float*)d_in[5]};
  const float* w_c[4] = {(const float*)d_in[6], (const float*)d_in[7],
                         (const float*)d_in[8], (const float*)d_in[9]};
  const float* omega_s = (const float*)d_in[10];
  const float* omega_c = (const float*)d_in[11];
  const float* w1 = (const float*)d_in[12];
  const float* b1 = (const float*)d_in[13];
  const float* w2 = (const float*)d_in[14];
  const float* b2 = (const float*)d_in[15];
  const float* ln_a[3] = {(const float*)d_in[16], (const float*)d_in[18], (const float*)d_in[20]};
  const float* ln_b[3] = {(const float*)d_in[17], (const float*)d_in[19], (const float*)d_in[21]};

  char* ws = (char*)d_ws;
  size_t off = 0;
  auto alloc = [&](size_t bytes) -> char* {
    char* p = ws + off;
    off += (bytes + 255) & ~(size_t)255;
    return p;
  };

  const size_t actB = (size_t)Mrows * Dm * sizeof(bf16);     // 16 MiB
  const size_t MB32 = (size_t)Mrows * 2048 * sizeof(bf16);   // 32 MiB

  bf16* wqkv = (bf16*)alloc((size_t)3072 * 1024 * 2);
  bf16* wo_sb = (bf16*)alloc((size_t)1024 * 1024 * 2);
  bf16* wq_cb = (bf16*)alloc((size_t)1024 * 1024 * 2);
  bf16* wkv  = (bf16*)alloc((size_t)2048 * 1024 * 2);
  bf16* wo_cb = (bf16*)alloc((size_t)1024 * 1024 * 2);
  bf16* w1b = (bf16*)alloc((size_t)Dff * Dm * 2);
  bf16* w2b = (bf16*)alloc((size_t)Dff * Dm * 2);
  bf16* xnb  = (bf16*)alloc(actB);
  char* pool = alloc((size_t)Mrows * Dff * 2);               // 64 MiB shared pool
  bf16* qkvb = (bf16*)pool;                                  // 48 MiB (phase 1)
  bf16* kvb  = (bf16*)pool;                                  // 32 MiB (phase 2)
  bf16* qb   = (bf16*)(pool + MB32);                         // 16 MiB (phase 2)
  bf16* hb   = (bf16*)pool;                                  // 64 MiB (phase 3)
  bf16* attnb= (bf16*)alloc(actB);
  bf16* x2b  = (bf16*)alloc(actB);
  bf16* ln1b = (bf16*)alloc(actB);
  float* lto2 = (float*)alloc((size_t)Mrows * Dm * 4);
  bf16*  CSb  = (bf16*)alloc((size_t)32 * NCH * CSW * 2);
  float* stb  = (float*)alloc((size_t)32 * 8 * CSW * 4);
  bf16* fnb = xnb;   // xnb dead after QKV_s GEMM

  // ---- batched weight conversion ----
  {
    CvtA a;
    const float* srcs[10] = {w_s[0], w_s[1], w_s[2], w_s[3], w_c[0],
                             w_c[1], w_c[2], w_c[3], w1, w2};
    bf16* dsts[10] = {wqkv, wqkv + 1048576, wqkv + 2097152, wo_sb, wq_cb,
                      wkv, wkv + 1048576, wo_cb, w1b, w2b};
    const int SM = 262144, LG = 1048576;
    int st = 0;
    for (int i = 0; i < 10; ++i) {
      a.s[i] = srcs[i]; a.d[i] = dsts[i]; a.start[i] = st;
      st += (i < 8) ? SM : LG;
    }
    a.start[10] = st;
    cvt10<<<st / 256, 256, 0, stream>>>(a);
  }

  dim3 gperf(Sq / 128, Bq * 16);
  dim3 gseg(8, Bq * 16);
  const int gQKV = (Mrows / 128) * (3072 / 256);   // 768
  const int gKV  = (Mrows / 128) * (2048 / 256);   // 512
  const int gFF1 = (Mrows / 128) * (4096 / 256);   // 1024
  const int gN1k = (Mrows / 128) * (1024 / 256);   // 256

  // --- self performer on x ---
  ln_kernel<<<Mrows, 256, 0, stream>>>(x, ln_a[0], ln_b[0], xnb);
  gemmW<0><<<gQKV, 256, 0, stream>>>(xnb, wqkv, Mrows, 3072, 1024, nullptr, nullptr, nullptr, qkvb);
  perf_cs<<<gseg, 512, 0, stream>>>(qkvb + 1024, qkvb + 2048, 3072, omega_s, CSb, stb);
  perf_out<<<gperf, 256, 0, stream>>>(qkvb, 3072, omega_s, CSb, stb, attnb);
  gemmW<1><<<gN1k, 256, 0, stream>>>(attnb, wo_sb, Mrows, 1024, 1024, nullptr, x, nullptr, x2b);

  // --- cross performer: q from LN(lto), k/v from updated x ---
  ln_kernel<<<Mrows, 256, 0, stream>>>(lto, ln_a[1], ln_b[1], ln1b);
  gemmW<0><<<gN1k, 256, 0, stream>>>(ln1b, wq_cb, Mrows, 1024, 1024, nullptr, nullptr, nullptr, qb);
  gemmW<0><<<gKV, 256, 0, stream>>>(x2b, wkv, Mrows, 2048, 1024, nullptr, nullptr, nullptr, kvb);
  perf_cs<<<gseg, 512, 0, stream>>>(kvb, kvb + 1024, 2048, omega_c, CSb, stb);
  perf_out<<<gperf, 256, 0, stream>>>(qb, 1024, omega_c, CSb, stb, attnb);
  gemmW<2><<<gN1k, 256, 0, stream>>>(attnb, wo_cb, Mrows, 1024, 1024, nullptr, lto, lto2, nullptr);

  // --- FFN ---
  ln_kernel<<<Mrows, 256, 0, stream>>>(lto2, ln_a[2], ln_b[2], fnb);
  gemmW<3><<<gFF1, 256, 0, stream>>>(fnb, w1b, Mrows, 4096, 1024, b1, nullptr, nullptr, hb);
  gemmW<4><<<gN1k, 256, 0, stream>>>(hb, w2b, Mrows, 1024, 4096, b2, lto2, (float*)d_out, nullptr);
}

// Round 17
// 499.469 us; speedup vs baseline: 1.0777x; 1.0777x over previous
//
#include <hip/hip_runtime.h>
#include <cstdint>
#include <cstddef>

typedef __bf16 bf16;
typedef __bf16 bf16x8 __attribute__((ext_vector_type(8)));
typedef __bf16 bf16x4 __attribute__((ext_vector_type(4)));
typedef float  f32x4  __attribute__((ext_vector_type(4)));

#define NB 7
static constexpr int Bq = 2, Sq = 4096, Dm = 1024, Dff = 4096;
static constexpr int Mrows = Bq * Sq;     // 8192
static constexpr int NCH = Sq / 4;        // 1024 chunks per (b,h)
static constexpr int CSW = 464;           // padded prefix-state row width

template <int V> struct ic { static constexpr int value = V; };

__device__ __forceinline__ void gload16(const void* g, void* l) {
  __builtin_amdgcn_global_load_lds((__attribute__((address_space(1))) void*)g,
                                   (__attribute__((address_space(3))) void*)l,
                                   16, 0, 0);
}

template <int N> __device__ __forceinline__ void wait_vmcnt() {
  asm volatile("s_waitcnt vmcnt(%0)" :: "n"(N) : "memory");
}
__device__ __forceinline__ void wait_lgkm0() {
  asm volatile("s_waitcnt lgkmcnt(0)" ::: "memory");
}
__device__ __forceinline__ void SB() { __builtin_amdgcn_sched_barrier(0); }

__device__ __forceinline__ float gelu_f(float x) {
  const float c = 0.79788456080286535588f;
  float z = c * (x + 0.044715f * x * x * x);
  float t = 1.f - 2.f / (__expf(2.f * z) + 1.f);   // tanh(z)
  return 0.5f * x * (1.f + t);
}

// ---------------- batched f32 -> bf16 convert (10 regions, 1 launch) ----------
struct CvtA {
  const float* s[10];
  bf16* d[10];
  int start[11];
};
__global__ __launch_bounds__(256) void cvt10(CvtA a) {
  const int i = blockIdx.x * 256 + threadIdx.x;
  int r = 0;
#pragma unroll
  for (int k = 1; k < 10; ++k) r += (i >= a.start[k]);
  const int o = i - a.start[r];
  f32x4 v = *(const f32x4*)&a.s[r][(size_t)o * 4];
  bf16x4 ov;
#pragma unroll
  for (int e = 0; e < 4; ++e) ov[e] = (bf16)v[e];
  *(bf16x4*)&a.d[r][(size_t)o * 4] = ov;
}

// ---------------- LayerNorm (ddof=1, /(std+eps)) -> bf16 ----------------
__global__ __launch_bounds__(256) void ln_kernel(const float* __restrict__ x,
                                                 const float* __restrict__ alpha,
                                                 const float* __restrict__ beta,
                                                 bf16* __restrict__ out) {
  const int row = blockIdx.x, tid = threadIdx.x;
  const float* xr = x + (size_t)row * Dm;
  f32x4 v = *(const f32x4*)&xr[tid * 4];
  float s  = v[0] + v[1] + v[2] + v[3];
  float s2 = v[0]*v[0] + v[1]*v[1] + v[2]*v[2] + v[3]*v[3];
#pragma unroll
  for (int o = 32; o > 0; o >>= 1) { s += __shfl_xor(s, o); s2 += __shfl_xor(s2, o); }
  __shared__ float red[8];
  const int wid = tid >> 6, lane = tid & 63;
  if (lane == 0) { red[wid] = s; red[wid + 4] = s2; }
  __syncthreads();
  s  = red[0] + red[1] + red[2] + red[3];
  s2 = red[4] + red[5] + red[6] + red[7];
  const float mean = s * (1.f / 1024.f);
  float var = (s2 - s * mean) * (1.f / 1023.f);
  var = fmaxf(var, 0.f);
  const float inv = 1.f / (sqrtf(var) + 1e-6f);
  f32x4 a4 = *(const f32x4*)&alpha[tid * 4];
  f32x4 b4 = *(const f32x4*)&beta[tid * 4];
  bf16x4 o4;
#pragma unroll
  for (int e = 0; e < 4; ++e) o4[e] = (bf16)(a4[e] * (v[e] - mean) * inv + b4[e]);
  *(bf16x4*)&out[(size_t)row * Dm + tid * 4] = o4;
}

// ------------- 128x128 double-buffered GEMM, 256 threads, 2 blocks/CU -------------
// r15 base + MFMA ISSUE REORDER: kh outermost so 16 INDEPENDENT MFMAs separate
// the dependent k0->k1 reuse of each acc register (dependency distance ~77cy >>
// MFMA latency). Previously the k-pair was back-to-back: every odd MFMA stalled
// on its predecessor's result -- the invariant across all seven 28%-plateau
// variants. Same math, same summation order per acc; only issue order changes.
// MODE 0: out bf16 | 1: +res(f32)->bf16 | 2: +res(f32)->f32 | 3: +bias,gelu->bf16
// MODE 4: +bias+res(f32)->f32
template <int MODE>
__global__ __launch_bounds__(256, 2) void gemm128(
    const bf16* __restrict__ A, const bf16* __restrict__ Bw,
    int M, int N, int K,
    const float* __restrict__ bias, const float* __restrict__ res,
    float* __restrict__ outF, bf16* __restrict__ outB) {
  __shared__ __align__(16) char lds[65536];

  const int tid = threadIdx.x;
  const int lane = tid & 63, wid = tid >> 6;
  const int wm = wid >> 1, wn = wid & 1;

  // ---- supertile 8x8 mapping ----
  const int nwg = gridDim.x;
  const int nc = N >> 7;
  const int nsc = nc >> 3;
  const int lin = (blockIdx.x & 7) * (nwg >> 3) + (blockIdx.x >> 3);
  const int s = lin >> 6, w = lin & 63;
  const int sr = s / nsc, sc = s - sr * nsc;
  const int bm = (sr * 8 + (w >> 3)) * 128;
  const int bn = (sc * 8 + (w & 7)) * 128;
  const int NT = K >> 6;

  const int srow = tid >> 3;
  const int scol = ((tid & 7) ^ (srow & 7)) * 8;
  const bf16* pSA = A  + (size_t)(bm + srow) * K + scol;
  const bf16* pSB = Bw + (size_t)(bn + srow) * K + scol;
  const size_t cK = (size_t)32 * K;
  const int stDa = wid * 1024;

  auto stage = [&](int buf, const bf16* sa, const bf16* sb) {
#pragma unroll
    for (int c = 0; c < 4; ++c) {
      gload16(sa + (size_t)c * cK, &lds[buf * 16384 + c * 4096 + stDa]);
      gload16(sb + (size_t)c * cK, &lds[32768 + buf * 16384 + c * 4096 + stDa]);
    }
  };

  const int lr = lane & 15, uo = lane >> 4;
  const int rdA0 = (wm * 64 + lr) * 128 + ((uo)     ^ (lr & 7)) * 16;
  const int rdA1 = (wm * 64 + lr) * 128 + ((4 + uo) ^ (lr & 7)) * 16;
  const int rdB0 = 32768 + (wn * 64 + lr) * 128 + ((uo)     ^ (lr & 7)) * 16;
  const int rdB1 = 32768 + (wn * 64 + lr) * 128 + ((4 + uo) ^ (lr & 7)) * 16;

  f32x4 acc[4][4] = {};
  bf16x8 a[4][2], b[4][2];

  stage(0, pSA, pSB);
  stage(1, pSA + 64, pSB + 64);
  pSA += 128; pSB += 128;
  wait_vmcnt<8>();
  __builtin_amdgcn_s_barrier();

  auto TILE = [&](auto BUFC, int tt) {
    constexpr int BUF = decltype(BUFC)::value;
#pragma unroll
    for (int i = 0; i < 4; ++i) {
      a[i][0] = *(const bf16x8*)&lds[rdA0 + BUF * 16384 + i * 2048];
      a[i][1] = *(const bf16x8*)&lds[rdA1 + BUF * 16384 + i * 2048];
    }
#pragma unroll
    for (int j = 0; j < 4; ++j) {
      b[j][0] = *(const bf16x8*)&lds[rdB0 + BUF * 16384 + j * 2048];
      b[j][1] = *(const bf16x8*)&lds[rdB1 + BUF * 16384 + j * 2048];
    }
    wait_lgkm0(); SB();
    __builtin_amdgcn_s_barrier(); SB();

    if (tt + 2 < NT) stage(BUF, pSA + (size_t)(tt & 1) * 64,
                                pSB + (size_t)(tt & 1) * 64);
    // kh OUTERMOST: 16 independent MFMAs between dependent acc reuses
#pragma unroll
    for (int kh = 0; kh < 2; ++kh)
#pragma unroll
      for (int i = 0; i < 4; ++i)
#pragma unroll
        for (int j = 0; j < 4; ++j)
          acc[i][j] = __builtin_amdgcn_mfma_f32_16x16x32_bf16(
              a[i][kh], b[j][kh], acc[i][j], 0, 0, 0);
    SB();
    if (tt < NT - 2) wait_vmcnt<8>();
    else             wait_vmcnt<0>();
    __builtin_amdgcn_s_barrier(); SB();
  };

  for (int t = 0; t < NT; t += 2) {
    TILE(ic<0>{}, t);
    TILE(ic<1>{}, t + 1);
    pSA += 128; pSB += 128;
  }

  // ---- epilogue ----
#pragma unroll
  for (int f = 0; f < 4; ++f) {
    const int r0 = bm + wm * 64 + f * 16 + (lane >> 4) * 4;
#pragma unroll
    for (int g = 0; g < 4; ++g) {
      const int c = bn + wn * 64 + g * 16 + (lane & 15);
      float bv = 0.f;
      if (MODE == 3 || MODE == 4) bv = bias[c];
#pragma unroll
      for (int r = 0; r < 4; ++r) {
        const size_t idx = (size_t)(r0 + r) * N + c;
        float v = acc[f][g][r];
        if (MODE == 1 || MODE == 2) v += res[idx];
        if (MODE == 3) v = gelu_f(v + bv);
        if (MODE == 4) v += bv + res[idx];
        if (MODE == 0 || MODE == 1 || MODE == 3) outB[idx] = (bf16)v;
        else outF[idx] = v;
      }
    }
  }
}

// ------- fused Performer chunk-sums + segment scan (block = 1 segment) -------
// CS stored in bf16 (halves traffic); segtot (raw segment totals) stays f32.
__global__ __launch_bounds__(512) void perf_cs(
    const bf16* __restrict__ kmat, const bf16* __restrict__ vmat, int ld,
    const float* __restrict__ omega, bf16* __restrict__ CS,
    float* __restrict__ segtot) {
  const int tid = threadIdx.x;
  const int bh = blockIdx.y, b = bh >> 4, h = bh & 15;
  const int seg = blockIdx.x;
  const int s0 = seg * 512;
  __shared__ __align__(16) bf16 vs[512][64];   // XOR-swizzled, 64 KB
  __shared__ float kps[512][8];                // 16 KB
  __shared__ float oms[448];

  {
    const bf16* vb = vmat + ((size_t)(b * Sq + s0)) * ld + h * 64;
#pragma unroll
    for (int p = 0; p < 8; ++p) {
      const int row = p * 64 + (tid >> 3), c16 = (tid & 7) * 8;
      *(uint4*)&vs[row][c16 ^ ((row & 7) * 8)] =
          *(const uint4*)&vb[(size_t)row * ld + c16];
    }
  }
  if (tid < 448) oms[tid] = omega[tid];
  __syncthreads();

  {
    const int row = tid;
    const bf16* kr = kmat + ((size_t)(b * Sq + s0 + row)) * ld + h * 64;
    bf16x8 kv[8];
#pragma unroll
    for (int q = 0; q < 8; ++q) kv[q] = *(const bf16x8*)&kr[q * 8];
    float f[NB];
#pragma unroll
    for (int n = 0; n < NB; ++n) f[n] = 0.f;
#pragma unroll
    for (int d = 0; d < 64; ++d) {
      const float kd = (float)kv[d >> 3][d & 7];
#pragma unroll
      for (int n = 0; n < NB; ++n) f[n] += kd * oms[n * 64 + d];
    }
    float sum = 1e-6f, e[NB];
#pragma unroll
    for (int n = 0; n < NB; ++n) { e[n] = __expf(-0.5f * f[n] * f[n]); sum += e[n]; }
    const float inv = 1.f / sum;
#pragma unroll
    for (int n = 0; n < NB; ++n) kps[row][n] = e[n] * inv;
    kps[row][7] = 0.f;
  }
  __syncthreads();

  if (tid < CSW) {
    const int comp = tid;
    bf16* outb = CS + ((size_t)bh * NCH + seg * 128) * CSW;
    float r = 0.f;
    if (comp < 8) {
      for (int c = 0; c < 128; ++c) {
        if (comp < 7)
          r += kps[4*c][comp] + kps[4*c+1][comp] + kps[4*c+2][comp] + kps[4*c+3][comp];
        outb[(size_t)c * CSW + comp] = (bf16)r;
      }
    } else if (comp < 456) {
      const int n = (comp - 8) >> 6, d = (comp - 8) & 63;
      for (int c = 0; c < 128; ++c) {
#pragma unroll
        for (int i = 0; i < 4; ++i) {
          const int row = 4 * c + i;
          r += kps[row][n] * (float)vs[row][d ^ ((row & 7) * 8)];
        }
        outb[(size_t)c * CSW + comp] = (bf16)r;
      }
    } else {
      for (int c = 0; c < 128; ++c) outb[(size_t)c * CSW + comp] = (bf16)0.f;
    }
    segtot[((size_t)bh * 8 + seg) * CSW + comp] = r;
  }
}

// ---------------- Performer output (computes its own segment prefix) ----------------
__global__ __launch_bounds__(256) void perf_out(
    const bf16* __restrict__ qmat, int ldq, const float* __restrict__ omega,
    const bf16* __restrict__ CS, const float* __restrict__ segtot,
    bf16* __restrict__ attn) {
  const int tid = threadIdx.x;
  const int bh = blockIdx.y, b = bh >> 4, h = bh & 15;
  const int s0 = blockIdx.x * 128;
  const int cg0 = s0 >> 2;
  const int seg = cg0 >> 7;
  __shared__ __align__(16) float Ps[32 * CSW];
  __shared__ float qps[128][8];
  __shared__ float oms[NB * 64];
  __shared__ float offs[CSW];

  for (int c = tid; c < CSW; c += 256) {
    float o = 0.f;
    for (int ss = 0; ss < seg; ++ss) o += segtot[((size_t)bh * 8 + ss) * CSW + c];
    offs[c] = o;
  }
  if (tid < 224) { oms[tid] = omega[tid]; oms[tid + 224] = omega[tid + 224]; }
  __syncthreads();

  {
    const bf16* src = CS + ((size_t)bh * NCH + cg0) * CSW;
    for (int i = tid; i < 32 * CSW / 4; i += 256) {
      bf16x4 a4 = *(const bf16x4*)&src[(size_t)i * 4];
      const int c0 = (i % (CSW / 4)) * 4;
      f32x4 o;
#pragma unroll
      for (int e = 0; e < 4; ++e) o[e] = (float)a4[e] + offs[c0 + e];
      *(f32x4*)&Ps[i * 4] = o;
    }
  }
  __syncthreads();
  {
    const int p = tid >> 1, half = tid & 1;
    const bf16* qr = qmat + ((size_t)(b * Sq + s0 + p)) * ldq + h * 64 + half * 32;
    bf16x8 qv[4];
#pragma unroll
    for (int q = 0; q < 4; ++q) qv[q] = *(const bf16x8*)&qr[q * 8];
    float f[NB];
#pragma unroll
    for (int n = 0; n < NB; ++n) f[n] = 0.f;
#pragma unroll
    for (int d = 0; d < 32; ++d) {
      float qd = (float)qv[d >> 3][d & 7];
#pragma unroll
      for (int n = 0; n < NB; ++n) f[n] += qd * oms[n * 64 + half * 32 + d];
    }
    float sum = 1e-6f;
    float e[NB];
#pragma unroll
    for (int n = 0; n < NB; ++n) {
      float full = f[n] + __shfl_xor(f[n], 1);
      e[n] = __expf(-0.5f * full * full);
      sum += e[n];
    }
    float inv = 1.f / sum;
    if (half == 0) {
      float den = 1e-6f;
      const float* Pr = &Ps[(p >> 2) * CSW];
#pragma unroll
      for (int n = 0; n < NB; ++n) {
        float qn = e[n] * inv;
        qps[p][n] = qn;
        den += qn * Pr[n];
      }
      qps[p][7] = 1.f / den;
    }
  }
  __syncthreads();
  {
    const int d = tid & 63, w = tid >> 6;
    for (int qq = w; qq < 128; qq += 4) {
      const float* Pr = &Ps[(qq >> 2) * CSW + 8 + d];
      float num = 0.f;
#pragma unroll
      for (int n = 0; n < NB; ++n) num += qps[qq][n] * Pr[n * 64];
      attn[((size_t)(b * Sq + s0 + qq)) * Dm + h * 64 + d] = (bf16)(num * qps[qq][7]);
    }
  }
}

// ---------------------------------------------------------------------------
extern "C" void kernel_launch(void* const* d_in, const int* in_sizes, int n_in,
                              void* d_out, int out_size, void* d_ws, size_t ws_size,
                              hipStream_t stream) {
  const float* x    = (const float*)d_in[0];
  const float* lto  = (const float*)d_in[1];
  const float* w_s[4] = {(const float*)d_in[2], (const float*)d_in[3],
                         (const float*)d_in[4], (const float*)d_in[5]};
  const float* w_c[4] = {(const float*)d_in[6], (const float*)d_in[7],
                         (const float*)d_in[8], (const float*)d_in[9]};
  const float* omega_s = (const float*)d_in[10];
  const float* omega_c = (const float*)d_in[11];
  const float* w1 = (const float*)d_in[12];
  const float* b1 = (const float*)d_in[13];
  const float* w2 = (const float*)d_in[14];
  const float* b2 = (const float*)d_in[15];
  const float* ln_a[3] = {(const float*)d_in[16], (const float*)d_in[18], (const float*)d_in[20]};
  const float* ln_b[3] = {(const float*)d_in[17], (const float*)d_in[19], (const float*)d_in[21]};

  char* ws = (char*)d_ws;
  size_t off = 0;
  auto alloc = [&](size_t bytes) -> char* {
    char* p = ws + off;
    off += (bytes + 255) & ~(size_t)255;
    return p;
  };

  const size_t actB = (size_t)Mrows * Dm * sizeof(bf16);     // 16 MiB
  const size_t MB32 = (size_t)Mrows * 2048 * sizeof(bf16);   // 32 MiB

  bf16* wqkv = (bf16*)alloc((size_t)3072 * 1024 * 2);
  bf16* wo_sb = (bf16*)alloc((size_t)1024 * 1024 * 2);
  bf16* wq_cb = (bf16*)alloc((size_t)1024 * 1024 * 2);
  bf16* wkv  = (bf16*)alloc((size_t)2048 * 1024 * 2);
  bf16* wo_cb = (bf16*)alloc((size_t)1024 * 1024 * 2);
  bf16* w1b = (bf16*)alloc((size_t)Dff * Dm * 2);
  bf16* w2b = (bf16*)alloc((size_t)Dff * Dm * 2);
  bf16* xnb  = (bf16*)alloc(actB);
  char* pool = alloc((size_t)Mrows * Dff * 2);               // 64 MiB shared pool
  bf16* qkvb = (bf16*)pool;                                  // 48 MiB (phase 1)
  bf16* kvb  = (bf16*)pool;                                  // 32 MiB (phase 2)
  bf16* qb   = (bf16*)(pool + MB32);                         // 16 MiB (phase 2)
  bf16* hb   = (bf16*)pool;                                  // 64 MiB (phase 3)
  bf16* attnb= (bf16*)alloc(actB);
  bf16* x2b  = (bf16*)alloc(actB);
  bf16* ln1b = (bf16*)alloc(actB);
  float* lto2 = (float*)alloc((size_t)Mrows * Dm * 4);
  bf16*  CSb  = (bf16*)alloc((size_t)32 * NCH * CSW * 2);
  float* stb  = (float*)alloc((size_t)32 * 8 * CSW * 4);
  bf16* fnb = xnb;   // xnb dead after QKV_s GEMM

  // ---- batched weight conversion ----
  {
    CvtA a;
    const float* srcs[10] = {w_s[0], w_s[1], w_s[2], w_s[3], w_c[0],
                             w_c[1], w_c[2], w_c[3], w1, w2};
    bf16* dsts[10] = {wqkv, wqkv + 1048576, wqkv + 2097152, wo_sb, wq_cb,
                      wkv, wkv + 1048576, wo_cb, w1b, w2b};
    const int SM = 262144, LG = 1048576;
    int st = 0;
    for (int i = 0; i < 10; ++i) {
      a.s[i] = srcs[i]; a.d[i] = dsts[i]; a.start[i] = st;
      st += (i < 8) ? SM : LG;
    }
    a.start[10] = st;
    cvt10<<<st / 256, 256, 0, stream>>>(a);
  }

  dim3 gperf(Sq / 128, Bq * 16);
  dim3 gseg(8, Bq * 16);
  const int gQKV = (Mrows / 128) * (3072 / 128);   // 1536
  const int gKV  = (Mrows / 128) * (2048 / 128);   // 1024
  const int gFF1 = (Mrows / 128) * (4096 / 128);   // 2048
  const int gN1k = (Mrows / 128) * (1024 / 128);   // 512

  // --- self performer on x ---
  ln_kernel<<<Mrows, 256, 0, stream>>>(x, ln_a[0], ln_b[0], xnb);
  gemm128<0><<<gQKV, 256, 0, stream>>>(xnb, wqkv, Mrows, 3072, 1024, nullptr, nullptr, nullptr, qkvb);
  perf_cs<<<gseg, 512, 0, stream>>>(qkvb + 1024, qkvb + 2048, 3072, omega_s, CSb, stb);
  perf_out<<<gperf, 256, 0, stream>>>(qkvb, 3072, omega_s, CSb, stb, attnb);
  gemm128<1><<<gN1k, 256, 0, stream>>>(attnb, wo_sb, Mrows, 1024, 1024, nullptr, x, nullptr, x2b);

  // --- cross performer: q from LN(lto), k/v from updated x ---
  ln_kernel<<<Mrows, 256, 0, stream>>>(lto, ln_a[1], ln_b[1], ln1b);
  gemm128<0><<<gN1k, 256, 0, stream>>>(ln1b, wq_cb, Mrows, 1024, 1024, nullptr, nullptr, nullptr, qb);
  gemm128<0><<<gKV, 256, 0, stream>>>(x2b, wkv, Mrows, 2048, 1024, nullptr, nullptr, nullptr, kvb);
  perf_cs<<<gseg, 512, 0, stream>>>(kvb, kvb + 1024, 2048, omega_c, CSb, stb);
  perf_out<<<gperf, 256, 0, stream>>>(qb, 1024, omega_c, CSb, stb, attnb);
  gemm128<2><<<gN1k, 256, 0, stream>>>(attnb, wo_cb, Mrows, 1024, 1024, nullptr, lto, lto2, nullptr);

  // --- FFN ---
  ln_kernel<<<Mrows, 256, 0, stream>>>(lto2, ln_a[2], ln_b[2], fnb);
  gemm128<3><<<gFF1, 256, 0, stream>>>(fnb, w1b, Mrows, 4096, 1024, b1, nullptr, nullptr, hb);
  gemm128<4><<<gN1k, 256, 0, stream>>>(hb, w2b, Mrows, 1024, 4096, b2, lto2, (float*)d_out, nullptr);
}

// Round 18
// 492.407 us; speedup vs baseline: 1.0932x; 1.0143x over previous
//
#include <hip/hip_runtime.h>
#include <cstdint>
#include <cstddef>

typedef __bf16 bf16;
typedef __bf16 bf16x8 __attribute__((ext_vector_type(8)));
typedef __bf16 bf16x4 __attribute__((ext_vector_type(4)));
typedef float  f32x4  __attribute__((ext_vector_type(4)));

#define NB 7
static constexpr int Bq = 2, Sq = 4096, Dm = 1024, Dff = 4096;
static constexpr int Mrows = Bq * Sq;     // 8192
static constexpr int NCH = Sq / 4;        // 1024 chunks per (b,h)
static constexpr int CSW = 464;           // padded prefix-state row width

template <int V> struct ic { static constexpr int value = V; };

__device__ __forceinline__ void gload16(const void* g, void* l) {
  __builtin_amdgcn_global_load_lds((__attribute__((address_space(1))) void*)g,
                                   (__attribute__((address_space(3))) void*)l,
                                   16, 0, 0);
}

template <int N> __device__ __forceinline__ void wait_vmcnt() {
  asm volatile("s_waitcnt vmcnt(%0)" :: "n"(N) : "memory");
}
__device__ __forceinline__ void wait_lgkm0() {
  asm volatile("s_waitcnt lgkmcnt(0)" ::: "memory");
}
__device__ __forceinline__ void SB() { __builtin_amdgcn_sched_barrier(0); }

__device__ __forceinline__ float gelu_f(float x) {
  const float c = 0.79788456080286535588f;
  float z = c * (x + 0.044715f * x * x * x);
  float t = 1.f - 2.f / (__expf(2.f * z) + 1.f);   // tanh(z)
  return 0.5f * x * (1.f + t);
}

// ------- batched f32 -> bf16 convert (10 regions, 1 launch, 8 floats/thread) -------
struct CvtA {
  const float* s[10];
  bf16* d[10];
  int start[11];   // region boundaries in 8-float units
};
__global__ __launch_bounds__(256) void cvt10(CvtA a) {
  const int i = blockIdx.x * 256 + threadIdx.x;
  int r = 0;
#pragma unroll
  for (int k = 1; k < 10; ++k) r += (i >= a.start[k]);
  const size_t o = (size_t)(i - a.start[r]) * 8;
  f32x4 v0 = *(const f32x4*)&a.s[r][o];
  f32x4 v1 = *(const f32x4*)&a.s[r][o + 4];
  bf16x8 ov;
#pragma unroll
  for (int e = 0; e < 4; ++e) { ov[e] = (bf16)v0[e]; ov[4 + e] = (bf16)v1[e]; }
  *(bf16x8*)&a.d[r][o] = ov;
}

// ---------- LayerNorm (ddof=1, /(std+eps)) -> bf16, one row per WAVE ----------
// 4 rows/block, no LDS, no __syncthreads: 64-lane shfl reduction only.
__global__ __launch_bounds__(256) void ln_kernel(const float* __restrict__ x,
                                                 const float* __restrict__ alpha,
                                                 const float* __restrict__ beta,
                                                 bf16* __restrict__ out) {
  const int lane = threadIdx.x & 63;
  const int row  = blockIdx.x * 4 + (threadIdx.x >> 6);
  const float* xr = x + (size_t)row * Dm;
  f32x4 v[4];
  float s = 0.f, s2 = 0.f;
#pragma unroll
  for (int c = 0; c < 4; ++c) {
    v[c] = *(const f32x4*)&xr[c * 256 + lane * 4];
#pragma unroll
    for (int e = 0; e < 4; ++e) { s += v[c][e]; s2 += v[c][e] * v[c][e]; }
  }
#pragma unroll
  for (int o = 32; o > 0; o >>= 1) { s += __shfl_xor(s, o); s2 += __shfl_xor(s2, o); }
  const float mean = s * (1.f / 1024.f);
  float var = (s2 - s * mean) * (1.f / 1023.f);
  var = fmaxf(var, 0.f);
  const float inv = 1.f / (sqrtf(var) + 1e-6f);
#pragma unroll
  for (int c = 0; c < 4; ++c) {
    f32x4 a4 = *(const f32x4*)&alpha[c * 256 + lane * 4];
    f32x4 b4 = *(const f32x4*)&beta[c * 256 + lane * 4];
    bf16x4 o4;
#pragma unroll
    for (int e = 0; e < 4; ++e) o4[e] = (bf16)(a4[e] * (v[c][e] - mean) * inv + b4[e]);
    *(bf16x4*)&out[(size_t)row * Dm + c * 256 + lane * 4] = o4;
  }
}

// ------------- 128x128 double-buffered GEMM, 256 threads, 2 blocks/CU -------------
// Banked r15/r17 structure: homogeneous gload_lds staging queue + counted
// vmcnt(8); lgkm0+barrier before overwrite; compiler-interleaved stage/MFMA;
// kh-outermost MFMA order; XOR-swizzled LDS (0 conflicts); supertile 8x8
// XCD-contiguous L2 mapping (FETCH ~69MB on FFN1).
// MODE 0: out bf16 | 1: +res(f32)->bf16 | 2: +res(f32)->f32 | 3: +bias,gelu->bf16
// MODE 4: +bias+res(f32)->f32
template <int MODE>
__global__ __launch_bounds__(256, 2) void gemm128(
    const bf16* __restrict__ A, const bf16* __restrict__ Bw,
    int M, int N, int K,
    const float* __restrict__ bias, const float* __restrict__ res,
    float* __restrict__ outF, bf16* __restrict__ outB) {
  __shared__ __align__(16) char lds[65536];

  const int tid = threadIdx.x;
  const int lane = tid & 63, wid = tid >> 6;
  const int wm = wid >> 1, wn = wid & 1;

  // ---- supertile 8x8 mapping ----
  const int nwg = gridDim.x;
  const int nc = N >> 7;
  const int nsc = nc >> 3;
  const int lin = (blockIdx.x & 7) * (nwg >> 3) + (blockIdx.x >> 3);
  const int s = lin >> 6, w = lin & 63;
  const int sr = s / nsc, sc = s - sr * nsc;
  const int bm = (sr * 8 + (w >> 3)) * 128;
  const int bn = (sc * 8 + (w & 7)) * 128;
  const int NT = K >> 6;

  const int srow = tid >> 3;
  const int scol = ((tid & 7) ^ (srow & 7)) * 8;
  const bf16* pSA = A  + (size_t)(bm + srow) * K + scol;
  const bf16* pSB = Bw + (size_t)(bn + srow) * K + scol;
  const size_t cK = (size_t)32 * K;
  const int stDa = wid * 1024;

  auto stage = [&](int buf, const bf16* sa, const bf16* sb) {
#pragma unroll
    for (int c = 0; c < 4; ++c) {
      gload16(sa + (size_t)c * cK, &lds[buf * 16384 + c * 4096 + stDa]);
      gload16(sb + (size_t)c * cK, &lds[32768 + buf * 16384 + c * 4096 + stDa]);
    }
  };

  const int lr = lane & 15, uo = lane >> 4;
  const int rdA0 = (wm * 64 + lr) * 128 + ((uo)     ^ (lr & 7)) * 16;
  const int rdA1 = (wm * 64 + lr) * 128 + ((4 + uo) ^ (lr & 7)) * 16;
  const int rdB0 = 32768 + (wn * 64 + lr) * 128 + ((uo)     ^ (lr & 7)) * 16;
  const int rdB1 = 32768 + (wn * 64 + lr) * 128 + ((4 + uo) ^ (lr & 7)) * 16;

  f32x4 acc[4][4] = {};
  bf16x8 a[4][2], b[4][2];

  stage(0, pSA, pSB);
  stage(1, pSA + 64, pSB + 64);
  pSA += 128; pSB += 128;
  wait_vmcnt<8>();
  __builtin_amdgcn_s_barrier();

  auto TILE = [&](auto BUFC, int tt) {
    constexpr int BUF = decltype(BUFC)::value;
#pragma unroll
    for (int i = 0; i < 4; ++i) {
      a[i][0] = *(const bf16x8*)&lds[rdA0 + BUF * 16384 + i * 2048];
      a[i][1] = *(const bf16x8*)&lds[rdA1 + BUF * 16384 + i * 2048];
    }
#pragma unroll
    for (int j = 0; j < 4; ++j) {
      b[j][0] = *(const bf16x8*)&lds[rdB0 + BUF * 16384 + j * 2048];
      b[j][1] = *(const bf16x8*)&lds[rdB1 + BUF * 16384 + j * 2048];
    }
    wait_lgkm0(); SB();
    __builtin_amdgcn_s_barrier(); SB();

    if (tt + 2 < NT) stage(BUF, pSA + (size_t)(tt & 1) * 64,
                                pSB + (size_t)(tt & 1) * 64);
#pragma unroll
    for (int kh = 0; kh < 2; ++kh)
#pragma unroll
      for (int i = 0; i < 4; ++i)
#pragma unroll
        for (int j = 0; j < 4; ++j)
          acc[i][j] = __builtin_amdgcn_mfma_f32_16x16x32_bf16(
              a[i][kh], b[j][kh], acc[i][j], 0, 0, 0);
    SB();
    if (tt < NT - 2) wait_vmcnt<8>();
    else             wait_vmcnt<0>();
    __builtin_amdgcn_s_barrier(); SB();
  };

  for (int t = 0; t < NT; t += 2) {
    TILE(ic<0>{}, t);
    TILE(ic<1>{}, t + 1);
    pSA += 128; pSB += 128;
  }

  // ---- epilogue ----
#pragma unroll
  for (int f = 0; f < 4; ++f) {
    const int r0 = bm + wm * 64 + f * 16 + (lane >> 4) * 4;
#pragma unroll
    for (int g = 0; g < 4; ++g) {
      const int c = bn + wn * 64 + g * 16 + (lane & 15);
      float bv = 0.f;
      if (MODE == 3 || MODE == 4) bv = bias[c];
#pragma unroll
      for (int r = 0; r < 4; ++r) {
        const size_t idx = (size_t)(r0 + r) * N + c;
        float v = acc[f][g][r];
        if (MODE == 1 || MODE == 2) v += res[idx];
        if (MODE == 3) v = gelu_f(v + bv);
        if (MODE == 4) v += bv + res[idx];
        if (MODE == 0 || MODE == 1 || MODE == 3) outB[idx] = (bf16)v;
        else outF[idx] = v;
      }
    }
  }
}

// ------- fused Performer chunk-sums + segment scan (block = 1 segment) -------
// CS stored in bf16 (halves traffic); segtot (raw segment totals) stays f32.
__global__ __launch_bounds__(512) void perf_cs(
    const bf16* __restrict__ kmat, const bf16* __restrict__ vmat, int ld,
    const float* __restrict__ omega, bf16* __restrict__ CS,
    float* __restrict__ segtot) {
  const int tid = threadIdx.x;
  const int bh = blockIdx.y, b = bh >> 4, h = bh & 15;
  const int seg = blockIdx.x;
  const int s0 = seg * 512;
  __shared__ __align__(16) bf16 vs[512][64];   // XOR-swizzled, 64 KB
  __shared__ float kps[512][8];                // 16 KB
  __shared__ float oms[448];

  {
    const bf16* vb = vmat + ((size_t)(b * Sq + s0)) * ld + h * 64;
#pragma unroll
    for (int p = 0; p < 8; ++p) {
      const int row = p * 64 + (tid >> 3), c16 = (tid & 7) * 8;
      *(uint4*)&vs[row][c16 ^ ((row & 7) * 8)] =
          *(const uint4*)&vb[(size_t)row * ld + c16];
    }
  }
  if (tid < 448) oms[tid] = omega[tid];
  __syncthreads();

  {
    const int row = tid;
    const bf16* kr = kmat + ((size_t)(b * Sq + s0 + row)) * ld + h * 64;
    bf16x8 kv[8];
#pragma unroll
    for (int q = 0; q < 8; ++q) kv[q] = *(const bf16x8*)&kr[q * 8];
    float f[NB];
#pragma unroll
    for (int n = 0; n < NB; ++n) f[n] = 0.f;
#pragma unroll
    for (int d = 0; d < 64; ++d) {
      const float kd = (float)kv[d >> 3][d & 7];
#pragma unroll
      for (int n = 0; n < NB; ++n) f[n] += kd * oms[n * 64 + d];
    }
    float sum = 1e-6f, e[NB];
#pragma unroll
    for (int n = 0; n < NB; ++n) { e[n] = __expf(-0.5f * f[n] * f[n]); sum += e[n]; }
    const float inv = 1.f / sum;
#pragma unroll
    for (int n = 0; n < NB; ++n) kps[row][n] = e[n] * inv;
    kps[row][7] = 0.f;
  }
  __syncthreads();

  if (tid < CSW) {
    const int comp = tid;
    bf16* outb = CS + ((size_t)bh * NCH + seg * 128) * CSW;
    float r = 0.f;
    if (comp < 8) {
      for (int c = 0; c < 128; ++c) {
        if (comp < 7)
          r += kps[4*c][comp] + kps[4*c+1][comp] + kps[4*c+2][comp] + kps[4*c+3][comp];
        outb[(size_t)c * CSW + comp] = (bf16)r;
      }
    } else if (comp < 456) {
      const int n = (comp - 8) >> 6, d = (comp - 8) & 63;
      for (int c = 0; c < 128; ++c) {
#pragma unroll
        for (int i = 0; i < 4; ++i) {
          const int row = 4 * c + i;
          r += kps[row][n] * (float)vs[row][d ^ ((row & 7) * 8)];
        }
        outb[(size_t)c * CSW + comp] = (bf16)r;
      }
    } else {
      for (int c = 0; c < 128; ++c) outb[(size_t)c * CSW + comp] = (bf16)0.f;
    }
    segtot[((size_t)bh * 8 + seg) * CSW + comp] = r;
  }
}

// ---------------- Performer output (computes its own segment prefix) ----------------
__global__ __launch_bounds__(256) void perf_out(
    const bf16* __restrict__ qmat, int ldq, const float* __restrict__ omega,
    const bf16* __restrict__ CS, const float* __restrict__ segtot,
    bf16* __restrict__ attn) {
  const int tid = threadIdx.x;
  const int bh = blockIdx.y, b = bh >> 4, h = bh & 15;
  const int s0 = blockIdx.x * 128;
  const int cg0 = s0 >> 2;
  const int seg = cg0 >> 7;
  __shared__ __align__(16) float Ps[32 * CSW];
  __shared__ float qps[128][8];
  __shared__ float oms[NB * 64];
  __shared__ float offs[CSW];

  for (int c = tid; c < CSW; c += 256) {
    float o = 0.f;
    for (int ss = 0; ss < seg; ++ss) o += segtot[((size_t)bh * 8 + ss) * CSW + c];
    offs[c] = o;
  }
  if (tid < 224) { oms[tid] = omega[tid]; oms[tid + 224] = omega[tid + 224]; }
  __syncthreads();

  {
    const bf16* src = CS + ((size_t)bh * NCH + cg0) * CSW;
    for (int i = tid; i < 32 * CSW / 4; i += 256) {
      bf16x4 a4 = *(const bf16x4*)&src[(size_t)i * 4];
      const int c0 = (i % (CSW / 4)) * 4;
      f32x4 o;
#pragma unroll
      for (int e = 0; e < 4; ++e) o[e] = (float)a4[e] + offs[c0 + e];
      *(f32x4*)&Ps[i * 4] = o;
    }
  }
  __syncthreads();
  {
    const int p = tid >> 1, half = tid & 1;
    const bf16* qr = qmat + ((size_t)(b * Sq + s0 + p)) * ldq + h * 64 + half * 32;
    bf16x8 qv[4];
#pragma unroll
    for (int q = 0; q < 4; ++q) qv[q] = *(const bf16x8*)&qr[q * 8];
    float f[NB];
#pragma unroll
    for (int n = 0; n < NB; ++n) f[n] = 0.f;
#pragma unroll
    for (int d = 0; d < 32; ++d) {
      float qd = (float)qv[d >> 3][d & 7];
#pragma unroll
      for (int n = 0; n < NB; ++n) f[n] += qd * oms[n * 64 + half * 32 + d];
    }
    float sum = 1e-6f;
    float e[NB];
#pragma unroll
    for (int n = 0; n < NB; ++n) {
      float full = f[n] + __shfl_xor(f[n], 1);
      e[n] = __expf(-0.5f * full * full);
      sum += e[n];
    }
    float inv = 1.f / sum;
    if (half == 0) {
      float den = 1e-6f;
      const float* Pr = &Ps[(p >> 2) * CSW];
#pragma unroll
      for (int n = 0; n < NB; ++n) {
        float qn = e[n] * inv;
        qps[p][n] = qn;
        den += qn * Pr[n];
      }
      qps[p][7] = 1.f / den;
    }
  }
  __syncthreads();
  {
    const int d = tid & 63, w = tid >> 6;
    for (int qq = w; qq < 128; qq += 4) {
      const float* Pr = &Ps[(qq >> 2) * CSW + 8 + d];
      float num = 0.f;
#pragma unroll
      for (int n = 0; n < NB; ++n) num += qps[qq][n] * Pr[n * 64];
      attn[((size_t)(b * Sq + s0 + qq)) * Dm + h * 64 + d] = (bf16)(num * qps[qq][7]);
    }
  }
}

// ---------------------------------------------------------------------------
extern "C" void kernel_launch(void* const* d_in, const int* in_sizes, int n_in,
                              void* d_out, int out_size, void* d_ws, size_t ws_size,
                              hipStream_t stream) {
  const float* x    = (const float*)d_in[0];
  const float* lto  = (const float*)d_in[1];
  const float* w_s[4] = {(const float*)d_in[2], (const float*)d_in[3],
                         (const float*)d_in[4], (const float*)d_in[5]};
  const float* w_c[4] = {(const float*)d_in[6], (const float*)d_in[7],
                         (const float*)d_in[8], (const float*)d_in[9]};
  const float* omega_s = (const float*)d_in[10];
  const float* omega_c = (const float*)d_in[11];
  const float* w1 = (const float*)d_in[12];
  const float* b1 = (const float*)d_in[13];
  const float* w2 = (const float*)d_in[14];
  const float* b2 = (const float*)d_in[15];
  const float* ln_a[3] = {(const float*)d_in[16], (const float*)d_in[18], (const float*)d_in[20]};
  const float* ln_b[3] = {(const float*)d_in[17], (const float*)d_in[19], (const float*)d_in[21]};

  char* ws = (char*)d_ws;
  size_t off = 0;
  auto alloc = [&](size_t bytes) -> char* {
    char* p = ws + off;
    off += (bytes + 255) & ~(size_t)255;
    return p;
  };

  const size_t actB = (size_t)Mrows * Dm * sizeof(bf16);     // 16 MiB
  const size_t MB32 = (size_t)Mrows * 2048 * sizeof(bf16);   // 32 MiB

  bf16* wqkv = (bf16*)alloc((size_t)3072 * 1024 * 2);
  bf16* wo_sb = (bf16*)alloc((size_t)1024 * 1024 * 2);
  bf16* wq_cb = (bf16*)alloc((size_t)1024 * 1024 * 2);
  bf16* wkv  = (bf16*)alloc((size_t)2048 * 1024 * 2);
  bf16* wo_cb = (bf16*)alloc((size_t)1024 * 1024 * 2);
  bf16* w1b = (bf16*)alloc((size_t)Dff * Dm * 2);
  bf16* w2b = (bf16*)alloc((size_t)Dff * Dm * 2);
  bf16* xnb  = (bf16*)alloc(actB);
  char* pool = alloc((size_t)Mrows * Dff * 2);               // 64 MiB shared pool
  bf16* qkvb = (bf16*)pool;                                  // 48 MiB (phase 1)
  bf16* kvb  = (bf16*)pool;                                  // 32 MiB (phase 2)
  bf16* qb   = (bf16*)(pool + MB32);                         // 16 MiB (phase 2)
  bf16* hb   = (bf16*)pool;                                  // 64 MiB (phase 3)
  bf16* attnb= (bf16*)alloc(actB);
  bf16* x2b  = (bf16*)alloc(actB);
  bf16* ln1b = (bf16*)alloc(actB);
  float* lto2 = (float*)alloc((size_t)Mrows * Dm * 4);
  bf16*  CSb  = (bf16*)alloc((size_t)32 * NCH * CSW * 2);
  float* stb  = (float*)alloc((size_t)32 * 8 * CSW * 4);
  bf16* fnb = xnb;   // xnb dead after QKV_s GEMM

  // ---- batched weight conversion (8-float units) ----
  {
    CvtA a;
    const float* srcs[10] = {w_s[0], w_s[1], w_s[2], w_s[3], w_c[0],
                             w_c[1], w_c[2], w_c[3], w1, w2};
    bf16* dsts[10] = {wqkv, wqkv + 1048576, wqkv + 2097152, wo_sb, wq_cb,
                      wkv, wkv + 1048576, wo_cb, w1b, w2b};
    const int SM = 131072, LG = 524288;
    int st = 0;
    for (int i = 0; i < 10; ++i) {
      a.s[i] = srcs[i]; a.d[i] = dsts[i]; a.start[i] = st;
      st += (i < 8) ? SM : LG;
    }
    a.start[10] = st;                      // 2097152
    cvt10<<<st / 256, 256, 0, stream>>>(a);
  }

  dim3 gperf(Sq / 128, Bq * 16);
  dim3 gseg(8, Bq * 16);
  const int gQKV = (Mrows / 128) * (3072 / 128);   // 1536
  const int gKV  = (Mrows / 128) * (2048 / 128);   // 1024
  const int gFF1 = (Mrows / 128) * (4096 / 128);   // 2048
  const int gN1k = (Mrows / 128) * (1024 / 128);   // 512
  const int gLN  = Mrows / 4;                      // 2048

  // --- self performer on x ---
  ln_kernel<<<gLN, 256, 0, stream>>>(x, ln_a[0], ln_b[0], xnb);
  gemm128<0><<<gQKV, 256, 0, stream>>>(xnb, wqkv, Mrows, 3072, 1024, nullptr, nullptr, nullptr, qkvb);
  perf_cs<<<gseg, 512, 0, stream>>>(qkvb + 1024, qkvb + 2048, 3072, omega_s, CSb, stb);
  perf_out<<<gperf, 256, 0, stream>>>(qkvb, 3072, omega_s, CSb, stb, attnb);
  gemm128<1><<<gN1k, 256, 0, stream>>>(attnb, wo_sb, Mrows, 1024, 1024, nullptr, x, nullptr, x2b);

  // --- cross performer: q from LN(lto), k/v from updated x ---
  ln_kernel<<<gLN, 256, 0, stream>>>(lto, ln_a[1], ln_b[1], ln1b);
  gemm128<0><<<gN1k, 256, 0, stream>>>(ln1b, wq_cb, Mrows, 1024, 1024, nullptr, nullptr, nullptr, qb);
  gemm128<0><<<gKV, 256, 0, stream>>>(x2b, wkv, Mrows, 2048, 1024, nullptr, nullptr, nullptr, kvb);
  perf_cs<<<gseg, 512, 0, stream>>>(kvb, kvb + 1024, 2048, omega_c, CSb, stb);
  perf_out<<<gperf, 256, 0, stream>>>(qb, 1024, omega_c, CSb, stb, attnb);
  gemm128<2><<<gN1k, 256, 0, stream>>>(attnb, wo_cb, Mrows, 1024, 1024, nullptr, lto, lto2, nullptr);

  // --- FFN ---
  ln_kernel<<<gLN, 256, 0, stream>>>(lto2, ln_a[2], ln_b[2], fnb);
  gemm128<3><<<gFF1, 256, 0, stream>>>(fnb, w1b, Mrows, 4096, 1024, b1, nullptr, nullptr, hb);
  gemm128<4><<<gN1k, 256, 0, stream>>>(hb, w2b, Mrows, 1024, 4096, b2, lto2, (float*)d_out, nullptr);
}